// Round 5
// baseline (193.548 us; speedup 1.0000x reference)
//
#include <hip/hip_runtime.h>
#include <hip/hip_bf16.h>

// Problem constants
constexpr int B  = 128;
constexpr int C  = 235;
constexpr int N  = 21;
constexpr int HW = 4096;   // 64*64
constexpr int HO = 128;    // heads*fo
constexpr int E  = 41;     // 20 skeleton edges + 21 self loops

typedef __attribute__((ext_vector_type(8)))  short  short8;   // 8 bf16 (4 VGPRs)
typedef __attribute__((ext_vector_type(16))) float  f32x16;   // 32x32 accum

__device__ inline unsigned short bf16r(float x) {
    return __bfloat16_as_ushort(__float2bfloat16(x));   // RNE
}

// ---------------- K1: q[b,n,c] = sum_p t[b,n,p] * f[b,c,p] ----------------
// v5: contiguous-stream staging. Global reads are 1KB-contiguous per wave
// instruction (lanes 0-31 cover one row chunk); f32->bf16 conversion happens
// once at stage time; LDS holds bf16 tiles [64c][256k] + [21n][256k] with a
// 16B-granule XOR swizzle (slot ^= row&15) on both write and read sides.
// Inner loop: 2 ds_read_b128 + 1 MFMA. 4 waves = 2 c-subtiles x 2 k-halves.
// KSPLIT=2 -> 1024 blocks, chunked-XCD mapping co-locates the 4 c-blocks
// sharing one (b,ks) t-slice.
constexpr int KSPLIT = 2;
constexpr int KRANGE = HW / KSPLIT;   // 2048
constexpr int KSTAGE = 256;           // k per LDS stage
constexpr int NSLOT  = KSPLIT * 2;    // partial slots (ks x k-half)

__global__ __launch_bounds__(256) void k1_qgemm(
    const float* __restrict__ f,   // [B][C][HW]
    const float* __restrict__ t,   // [B][N][HW]
    float* __restrict__ qp)        // [NSLOT][B][N][C] partials
{
    __shared__ short8 fls[64 * 32];   // bf16 [row][32 granules of 8k], swizzled
    __shared__ short8 tls[21 * 32];

    // chunked XCD mapping: consecutive logical blocks (same b,ks; diff cblk)
    // land on the same XCD.
    const int j = blockIdx.x;
    const int logical = (j & 7) * 128 + (j >> 3);
    const int cblk = logical & 3;
    const int ks   = (logical >> 2) & 1;
    const int b    = logical >> 3;

    const int tid  = threadIdx.x;
    const int wave = tid >> 6;
    const int lane = tid & 63;
    const int l31  = lane & 31;
    const int kh   = lane >> 5;      // 8-k half within a 16-k MFMA step
    const int tc   = wave & 1;       // c sub-tile (0..1)
    const int kw   = wave >> 1;      // k-half of stage (0..1)

    const int c0 = cblk * 64;
    const float* fb = f + (size_t)b * C * HW;
    const float* tb = t + (size_t)b * N * HW;

    f32x16 acc = {};

    const int arow = (l31 < N) ? l31 : (N - 1);   // clamp A rows
    const int frow = tc * 32 + l31;               // f LDS row for B frag

    for (int st = 0; st < KRANGE / KSTAGE; ++st) {
        const int kst = ks * KRANGE + st * KSTAGE;
        __syncthreads();
        // stage f: 64 rows x 32 granules (8k f32 -> 8 bf16 = 16B). Lanes 0-31
        // cover one row's 1KB contiguously in global.
        #pragma unroll
        for (int i = 0; i < 8; i++) {
            const int v = tid + i * 256;
            const int r = v >> 5;
            const int s = v & 31;
            const int c = c0 + r;
            float4 x0 = make_float4(0.f, 0.f, 0.f, 0.f);
            float4 x1 = make_float4(0.f, 0.f, 0.f, 0.f);
            if (c < C) {
                const float* src = fb + (size_t)c * HW + kst + s * 8;
                x0 = *reinterpret_cast<const float4*>(src);
                x1 = *reinterpret_cast<const float4*>(src + 4);
            }
            union { short8 v8; unsigned short u[8]; } pk;
            pk.u[0] = bf16r(x0.x); pk.u[1] = bf16r(x0.y);
            pk.u[2] = bf16r(x0.z); pk.u[3] = bf16r(x0.w);
            pk.u[4] = bf16r(x1.x); pk.u[5] = bf16r(x1.y);
            pk.u[6] = bf16r(x1.z); pk.u[7] = bf16r(x1.w);
            fls[r * 32 + (s ^ (r & 15))] = pk.v8;
        }
        // stage t: 21 rows x 32 granules
        for (int v = tid; v < N * 32; v += 256) {
            const int r = v >> 5;
            const int s = v & 31;
            const float* src = tb + (size_t)r * HW + kst + s * 8;
            const float4 x0 = *reinterpret_cast<const float4*>(src);
            const float4 x1 = *reinterpret_cast<const float4*>(src + 4);
            union { short8 v8; unsigned short u[8]; } pk;
            pk.u[0] = bf16r(x0.x); pk.u[1] = bf16r(x0.y);
            pk.u[2] = bf16r(x0.z); pk.u[3] = bf16r(x0.w);
            pk.u[4] = bf16r(x1.x); pk.u[5] = bf16r(x1.y);
            pk.u[6] = bf16r(x1.z); pk.u[7] = bf16r(x1.w);
            tls[r * 32 + (s ^ (r & 15))] = pk.v8;
        }
        __syncthreads();

        // compute: wave's k-share = 128k = 8 MFMA steps of 16k
        #pragma unroll
        for (int it = 0; it < 8; it++) {
            const int kslot = kw * 16 + it * 2 + kh;   // 16B granule index
            const short8 av = tls[arow * 32 + (kslot ^ (arow & 15))];
            const short8 bv = fls[frow * 32 + (kslot ^ (frow & 15))];
            acc = __builtin_amdgcn_mfma_f32_32x32x16_bf16(av, bv, acc, 0, 0, 0);
        }
    }

    // C/D layout: col = lane&31, row = (reg&3) + 8*(reg>>2) + 4*(lane>>5)
    const int slot = ks * 2 + kw;
    float* qpk = qp + ((size_t)slot * B + b) * N * C;
    const int col = c0 + tc * 32 + l31;
    #pragma unroll
    for (int reg = 0; reg < 16; reg++) {
        const int row = (reg & 3) + 8 * (reg >> 2) + 4 * kh;
        if (row < N && col < C)
            qpk[row * C + col] = acc[reg];
    }
}

// ---------------- K1b: reduce NSLOT partials ----------------
__global__ __launch_bounds__(256) void k1b_reduce(
    const float* __restrict__ qp, float* __restrict__ q)
{
    const int i = blockIdx.x * 256 + threadIdx.x;
    constexpr int S = B * N * C;
    if (i < S) {
        float s = 0.f;
        #pragma unroll
        for (int p = 0; p < NSLOT; p++) s += qp[(size_t)p * S + i];
        q[i] = s;
    }
}

// ---------------- K2: BN stats per joint over (B, C) ----------------
__global__ __launch_bounds__(256) void k2_bnstats(
    const float* __restrict__ q,       // [B][N][C]
    const float* __restrict__ gamma,   // [N]
    const float* __restrict__ beta,    // [N]
    float* __restrict__ stats)         // [N][2] -> scale, shift
{
    const int n = blockIdx.x;
    const int tid = threadIdx.x;
    float s = 0.f, s2 = 0.f;
    if (tid < C) {
        for (int b = 0; b < B; b++) {
            const float v = q[((size_t)b * N + n) * C + tid];
            s += v; s2 += v * v;
        }
    }
    for (int off = 32; off; off >>= 1) {
        s  += __shfl_down(s,  off);
        s2 += __shfl_down(s2, off);
    }
    __shared__ float rs[4], rs2[4];
    const int wave = tid >> 6, lane = tid & 63;
    if (lane == 0) { rs[wave] = s; rs2[wave] = s2; }
    __syncthreads();
    if (tid == 0) {
        const float S  = rs[0] + rs[1] + rs[2] + rs[3];
        const float S2 = rs2[0] + rs2[1] + rs2[2] + rs2[3];
        const float cnt = (float)(B * C);
        const float mean = S / cnt;
        const float var  = S2 / cnt - mean * mean;
        const float scale = gamma[n] * rsqrtf(var + 1e-5f);
        stats[2 * n]     = scale;
        stats[2 * n + 1] = beta[n] - mean * scale;
    }
}

// ---------------- K3: BN-apply + LeakyReLU + GAT + Cheb ----------------
__global__ __launch_bounds__(256) void k3_tail(
    const float* __restrict__ q,        // [B][N][C]
    const float* __restrict__ stats,    // [N][2]
    const float* __restrict__ gatw,     // [C][HO]
    const float* __restrict__ attsrc,   // [4][32]
    const float* __restrict__ attdst,   // [4][32]
    const float* __restrict__ gatbias,  // [HO]
    const float* __restrict__ chebw,    // [2][HO][3]
    const float* __restrict__ chebbias, // [3]
    const float* __restrict__ adj,      // [N][N]
    const int* __restrict__ esrc,
    const int* __restrict__ edst,
    float* __restrict__ out)            // [B][N][3]
{
    __shared__ float ql[N][C + 1];
    __shared__ float Wl[48][HO];
    __shared__ float hl[N][HO];
    __shared__ float xl[N][HO];
    __shared__ float asrcl[N][4], adstl[N][4];
    __shared__ float el[E][4], alphal[E][4];
    __shared__ float mx[N][4], den[N][4];
    __shared__ float zl[N][3], t0l[N][3], dsl[N];
    __shared__ int esl[E], edl[E];

    const int b = blockIdx.x;
    const int tid = threadIdx.x;

    for (int v = tid; v < N * C; v += 256) {
        const int n = v / C, c = v % C;
        float x = q[((size_t)b * N + n) * C + c];
        x = x * stats[2 * n] + stats[2 * n + 1];
        ql[n][c] = (x >= 0.f) ? x : 0.1f * x;
    }
    if (tid < E) { esl[tid] = esrc[tid]; edl[tid] = edst[tid]; }
    for (int v = tid; v < N * HO; v += 256) hl[v >> 7][v & 127] = 0.f;
    __syncthreads();

    for (int k0 = 0; k0 < C; k0 += 48) {
        const int kc = (C - k0) < 48 ? (C - k0) : 48;
        for (int v = tid; v < kc * HO; v += 256) {
            const int kk = v >> 7, o = v & 127;
            Wl[kk][o] = gatw[(size_t)(k0 + kk) * HO + o];
        }
        __syncthreads();
        for (int idx = tid; idx < N * HO; idx += 256) {
            const int n = idx >> 7, o = idx & 127;
            float s = hl[n][o];
            for (int kk = 0; kk < kc; kk++)
                s += ql[n][k0 + kk] * Wl[kk][o];
            hl[n][o] = s;
        }
        __syncthreads();
    }

    if (tid < N * 4) {
        const int n = tid >> 2, h = tid & 3;
        float ss = 0.f, sd = 0.f;
        for (int fo = 0; fo < 32; fo++) {
            const float hv = hl[n][h * 32 + fo];
            ss += hv * attsrc[h * 32 + fo];
            sd += hv * attdst[h * 32 + fo];
        }
        asrcl[n][h] = ss; adstl[n][h] = sd;
    }
    __syncthreads();
    if (tid < E * 4) {
        const int e = tid >> 2, h = tid & 3;
        const float v = asrcl[esl[e]][h] + adstl[edl[e]][h];
        el[e][h] = (v >= 0.f) ? v : 0.2f * v;
    }
    __syncthreads();
    if (tid < N * 4) {
        const int n = tid >> 2, h = tid & 3;
        float m = -1e30f;
        for (int e = 0; e < E; e++)
            if (edl[e] == n) m = fmaxf(m, el[e][h]);
        mx[n][h] = m;
    }
    __syncthreads();
    if (tid < E * 4) {
        const int e = tid >> 2, h = tid & 3;
        el[e][h] = __expf(el[e][h] - mx[edl[e]][h]);
    }
    __syncthreads();
    if (tid < N * 4) {
        const int n = tid >> 2, h = tid & 3;
        float s = 0.f;
        for (int e = 0; e < E; e++)
            if (edl[e] == n) s += el[e][h];
        den[n][h] = s;
    }
    __syncthreads();
    if (tid < E * 4) {
        const int e = tid >> 2, h = tid & 3;
        alphal[e][h] = el[e][h] / den[edl[e]][h];
    }
    __syncthreads();

    for (int idx = tid; idx < N * HO; idx += 256) {
        const int n = idx >> 7, o = idx & 127, h = o >> 5;
        float s = 0.f;
        for (int e = 0; e < E; e++)
            if (edl[e] == n) s += alphal[e][h] * hl[esl[e]][o];
        xl[n][o] = s + gatbias[o];
    }
    if (tid < N) {
        float s = 0.f;
        for (int j2 = 0; j2 < N; j2++) s += adj[tid * N + j2];
        dsl[tid] = rsqrtf(s);
    }
    __syncthreads();

    if (tid < N * 3) {
        const int n = tid / 3, o = tid % 3;
        float s0 = 0.f, sz = 0.f;
        for (int c2 = 0; c2 < HO; c2++) {
            const float xv = xl[n][c2];
            s0 += xv * chebw[(size_t)c2 * 3 + o];
            sz += xv * chebw[(size_t)(HO + c2) * 3 + o];
        }
        t0l[n][o] = s0; zl[n][o] = sz;
    }
    __syncthreads();
    if (tid < N * 3) {
        const int m = tid / 3, o = tid % 3;
        float s = t0l[m][o] + zl[m][o];
        for (int n2 = 0; n2 < N; n2++)
            s -= dsl[m] * adj[m * N + n2] * dsl[n2] * zl[n2][o];
        out[(size_t)b * N * 3 + tid] = s + chebbias[o];
    }
}

extern "C" void kernel_launch(void* const* d_in, const int* in_sizes, int n_in,
                              void* d_out, int out_size, void* d_ws, size_t ws_size,
                              hipStream_t stream) {
    const float* feature  = (const float*)d_in[0];
    const float* target   = (const float*)d_in[1];
    const float* gamma    = (const float*)d_in[2];
    const float* beta     = (const float*)d_in[3];
    const float* gatw     = (const float*)d_in[4];
    const float* attsrc   = (const float*)d_in[5];
    const float* attdst   = (const float*)d_in[6];
    const float* gatbias  = (const float*)d_in[7];
    const float* chebw    = (const float*)d_in[8];
    const float* chebbias = (const float*)d_in[9];
    const float* adj      = (const float*)d_in[10];
    const int*   esrc     = (const int*)d_in[11];
    const int*   edst     = (const int*)d_in[12];

    constexpr int QS = B * N * C;
    float* qp    = (float*)d_ws;                    // [NSLOT][B][N][C]
    float* q     = qp + (size_t)NSLOT * QS;         // [B][N][C]
    float* stats = q + QS;                          // [N][2]
    float* out   = (float*)d_out;

    hipLaunchKernelGGL(k1_qgemm, dim3(4 * KSPLIT * B), dim3(256), 0, stream,
                       feature, target, qp);
    hipLaunchKernelGGL(k1b_reduce, dim3((QS + 255) / 256), dim3(256), 0, stream, qp, q);
    hipLaunchKernelGGL(k2_bnstats, dim3(N), dim3(256), 0, stream, q, gamma, beta, stats);
    hipLaunchKernelGGL(k3_tail, dim3(B), dim3(256), 0, stream,
                       q, stats, gatw, attsrc, attdst, gatbias, chebw, chebbias,
                       adj, esrc, edst, out);
}